// Round 12
// baseline (280.788 us; speedup 1.0000x reference)
//
#include <hip/hip_runtime.h>
#include <stdint.h>

#define KN 9
#define CC 128
#define FF 128
#define TM 32      // pixels per block (half an image row)
#define NT 256     // threads per block (4 waves)
#define LDK 136    // padded LDS K-stride (bf16); 272 B row, 16B-aligned
#define NBLK 1024  // 4 blocks/CU x 256 CU -- exactly co-resident

typedef __bf16 bf16x8 __attribute__((ext_vector_type(8)));
typedef float f32x4 __attribute__((ext_vector_type(4)));
typedef unsigned short us8 __attribute__((ext_vector_type(8)));

__constant__ float c_init_i[KN] = {0.f,0.f,1.f,2.f,2.f,1.f,0.f,2.f,1.f};
__constant__ float c_init_j[KN] = {0.f,1.f,1.f,2.f,0.f,2.f,1.f,0.f,2.f};

static __device__ inline float bf2f(unsigned short u) {
    union { unsigned u; float f; } v; v.u = ((unsigned)u) << 16; return v.f;
}

// issue 4 corner loads (8 bf16 channels) for pixel p_ into NAMED us8 regs
#define ISSUE(n_, p_, S) do {                                          \
    int lt_o = cB[p_][n_][0], rb_o = cB[p_][n_][1];                    \
    int rt_o = (rb_o & 0x7E000) | (lt_o & 0x1F80);                     \
    int lb_o = (lt_o & 0x7E000) | (rb_o & 0x1F80);                     \
    lt##S = *(const us8*)(bb16 + lt_o + icg);                          \
    rt##S = *(const us8*)(bb16 + rt_o + icg);                          \
    lb##S = *(const us8*)(bb16 + lb_o + icg);                          \
    rb##S = *(const us8*)(bb16 + rb_o + icg);                          \
    __builtin_amdgcn_sched_barrier(0);                                 \
  } while (0)

// bilinear interp of 8 channels + bf16 pack + one ds_write_b128
#define CONSUME(n_, p_, S, d_) do {                                    \
    float fy_ = cF[p_][n_][0], fx_ = cF[p_][n_][1];                    \
    us8 pk_;                                                           \
    _Pragma("unroll")                                                  \
    for (int j = 0; j < 8; ++j) {                                      \
      float v0_ = bf2f(lt##S[j]), v1_ = bf2f(rt##S[j]);                \
      float v2_ = bf2f(lb##S[j]), v3_ = bf2f(rb##S[j]);                \
      float vt_ = v0_ + (v1_ - v0_) * fy_;                             \
      float vb_ = v2_ + (v3_ - v2_) * fy_;                             \
      float r_  = vt_ + (vb_ - vt_) * fx_;                             \
      pk_[j] = __builtin_bit_cast(unsigned short, (__bf16)r_);         \
    }                                                                  \
    *(us8*)&As[d_][p_][icg] = pk_;                                     \
  } while (0)

// 8 B-fragments for tap n_ (this wave's 32-filter slice), direct from L2
#define LOADB(n_) do {                                                 \
    bfr0 = *(const us8*)(wbase + ((n_) << 14));                        \
    bfr1 = *(const us8*)(wbase + ((n_) << 14) + 512);                  \
    bfr2 = *(const us8*)(wbase + ((n_) << 14) + 4096);                 \
    bfr3 = *(const us8*)(wbase + ((n_) << 14) + 4096 + 512);           \
    bfr4 = *(const us8*)(wbase + ((n_) << 14) + 8192);                 \
    bfr5 = *(const us8*)(wbase + ((n_) << 14) + 8192 + 512);           \
    bfr6 = *(const us8*)(wbase + ((n_) << 14) + 12288);                \
    bfr7 = *(const us8*)(wbase + ((n_) << 14) + 12288 + 512);          \
    __builtin_amdgcn_sched_barrier(0);                                 \
  } while (0)

#define MSTEP(d_, ks_, B0, B1) do {                                    \
    bf16x8 a0_ = __builtin_bit_cast(bf16x8, *(const us8*)(&As[d_][col][(ks_) * 32 + quad * 8]));      \
    bf16x8 a1_ = __builtin_bit_cast(bf16x8, *(const us8*)(&As[d_][16 + col][(ks_) * 32 + quad * 8])); \
    acc00 = __builtin_amdgcn_mfma_f32_16x16x32_bf16(a0_, __builtin_bit_cast(bf16x8, B0), acc00, 0, 0, 0); \
    acc01 = __builtin_amdgcn_mfma_f32_16x16x32_bf16(a0_, __builtin_bit_cast(bf16x8, B1), acc01, 0, 0, 0); \
    acc10 = __builtin_amdgcn_mfma_f32_16x16x32_bf16(a1_, __builtin_bit_cast(bf16x8, B0), acc10, 0, 0, 0); \
    acc11 = __builtin_amdgcn_mfma_f32_16x16x32_bf16(a1_, __builtin_bit_cast(bf16x8, B1), acc11, 0, 0, 0); \
  } while (0)

#define MTAP(d_) do {                                                  \
    MSTEP(d_, 0, bfr0, bfr1); MSTEP(d_, 1, bfr2, bfr3);                \
    MSTEP(d_, 2, bfr4, bfr5); MSTEP(d_, 3, bfr6, bfr7);                \
  } while (0)

// lgkm-only barrier: drains ds_writes (As ready) and proves prior MFMA
// ds_reads done; global loads (gathers + B-frags) stay in flight across it.
#define BAR() do {                                                     \
    asm volatile("s_waitcnt lgkmcnt(0)" ::: "memory");                 \
    __builtin_amdgcn_s_barrier();                                      \
  } while (0)

// Fused prep + deform in ONE launch, manual grid barrier (no cooperative API
// -- R8 showed hipLaunchCooperativeKernel never executes under this harness's
// graph capture).  All NBLK blocks are exactly co-resident (4/CU, cap-128,
// 24KB LDS), so a device-scope atomic counter barrier cannot deadlock; the
// spin is additionally iteration-bounded (wrong-answer, never hang).
__launch_bounds__(NT, 4)
__global__ void fused_kernel(const float* __restrict__ x,
                             const float* __restrict__ off,
                             const float* __restrict__ Wk,
                             const float* __restrict__ bias,
                             float* __restrict__ out,
                             unsigned short* __restrict__ Wt,
                             unsigned short* __restrict__ xb,
                             unsigned int* __restrict__ flag) {
    __shared__ unsigned short As[2][TM][LDK];  // double-buffered: 8704 B
    __shared__ int   cB[TM][KN][2];            // packed lt/rb offsets: 2304 B
    __shared__ float cF[TM][KN][2];            // (fy, fx): 2304 B
    __shared__ unsigned short t[32][33];       // W-transpose scratch: 2112 B
    // total 24128 B; 4 blocks/CU -> 96.5 KB of 160 KB

    const int tid = threadIdx.x;
    const int blk = blockIdx.x;
    const int bb   = blk & 7;                  // XCD swizzle: image b -> XCD b
    const int rr   = blk >> 3;                 // 0..127: 32-pixel chunk
    const int pix0 = (bb << 12) + (rr << 5);

    // ---- A1: x fp32 -> bf16.  XCD-LOCAL mapping: this block converts slice
    // rr of ITS OWN image bb -- producer and consumer share one L2 under the
    // %8 XCD mapping (device fences below are the correctness mechanism). ----
    {
        const int base = (bb << 19) + (rr << 12) + tid * 16;
        float4 a0 = *(const float4*)(x + base);
        float4 a1 = *(const float4*)(x + base + 4);
        float4 a2 = *(const float4*)(x + base + 8);
        float4 a3 = *(const float4*)(x + base + 12);
        us8 o0, o1;
        o0[0] = __builtin_bit_cast(unsigned short, (__bf16)a0.x);
        o0[1] = __builtin_bit_cast(unsigned short, (__bf16)a0.y);
        o0[2] = __builtin_bit_cast(unsigned short, (__bf16)a0.z);
        o0[3] = __builtin_bit_cast(unsigned short, (__bf16)a0.w);
        o0[4] = __builtin_bit_cast(unsigned short, (__bf16)a1.x);
        o0[5] = __builtin_bit_cast(unsigned short, (__bf16)a1.y);
        o0[6] = __builtin_bit_cast(unsigned short, (__bf16)a1.z);
        o0[7] = __builtin_bit_cast(unsigned short, (__bf16)a1.w);
        o1[0] = __builtin_bit_cast(unsigned short, (__bf16)a2.x);
        o1[1] = __builtin_bit_cast(unsigned short, (__bf16)a2.y);
        o1[2] = __builtin_bit_cast(unsigned short, (__bf16)a2.z);
        o1[3] = __builtin_bit_cast(unsigned short, (__bf16)a2.w);
        o1[4] = __builtin_bit_cast(unsigned short, (__bf16)a3.x);
        o1[5] = __builtin_bit_cast(unsigned short, (__bf16)a3.y);
        o1[6] = __builtin_bit_cast(unsigned short, (__bf16)a3.z);
        o1[7] = __builtin_bit_cast(unsigned short, (__bf16)a3.w);
        *(us8*)(xb + base)     = o0;
        *(us8*)(xb + base + 8) = o1;
    }

    // ---- A2: W transpose -> Wt fragment-linear layout (blocks 0..143):
    //   slot s = (n*4+ks)*8 + nt, elem = s*512 + quad*128 + col*8 + e ----
    if (blk < 144) {
        const int n  = blk >> 4;
        const int tf = blk & 3;        // f-tile (2 nt slices)
        const int tc = (blk >> 2) & 3; // c-tile (ks)
        const int g  = tid >> 5;
        const int l  = tid & 31;
#pragma unroll
        for (int r = 0; r < 4; ++r) {
            int cl = g * 4 + r;
            t[cl][l] = __builtin_bit_cast(unsigned short,
                        (__bf16)Wk[(n << 14) + ((tc * 32 + cl) << 7) + (tf * 32 + l)]);
        }
        __syncthreads();               // block-uniform branch: legal
#pragma unroll
        for (int r = 0; r < 4; ++r) {
            int o   = r * 256 + tid;   // 0..1023 within this (n,ks,tf) tile
            int b   = o >> 9;          // nt = tf*2 + b
            int q   = (o >> 7) & 3;
            int col = (o >> 3) & 15;
            int e   = o & 7;
            Wt[(((n * 4 + tc) * 4 + tf) << 10) + o] = t[q * 8 + e][b * 16 + col];
        }
    }

    // ---- A3: packed corner offsets + fractions per (p, n) ----
    for (int tt = tid; tt < TM * KN; tt += NT) {
        int p = tt & (TM - 1);
        int n = tt >> 5;
        int pg = (rr << 5) + p;
        float2 o = *(const float2*)(off + (size_t)(pix0 + p) * (2 * KN) + 2 * n);
        float y  = (float)((pg >> 6) - 1) + c_init_i[n] + o.x;
        float xx = (float)((pg & 63) - 1) + c_init_j[n] + o.y;
        y  = fminf(fmaxf(y, 0.f), 63.f);
        xx = fminf(fmaxf(xx, 0.f), 63.f);
        float y0f = floorf(y), x0f = floorf(xx);
        int y0 = (int)y0f, x0 = (int)x0f;
        int y1 = (int)ceilf(y), x1 = (int)ceilf(xx);
        cB[p][n][0] = (y0 << 13) | (x0 << 7);   // lt element offset
        cB[p][n][1] = (y1 << 13) | (x1 << 7);   // rb element offset
        cF[p][n][0] = y - y0f;
        cF[p][n][1] = xx - x0f;
    }
    __syncthreads();   // block's stores to xb/Wt issued; coords in LDS

    // ---- manual grid barrier: device-scope release/acquire (G16) ----
    if (tid == 0) {
        __threadfence();   // agent fence: write back this block's xb/Wt
        __hip_atomic_fetch_add(flag, 1u, __ATOMIC_RELEASE, __HIP_MEMORY_SCOPE_AGENT);
        int guard = 0;
        while (__hip_atomic_load(flag, __ATOMIC_ACQUIRE, __HIP_MEMORY_SCOPE_AGENT) < NBLK) {
            __builtin_amdgcn_s_sleep(2);
            if (++guard > 1000000) break;   // bounded: wrong-answer, never hang
        }
    }
    __syncthreads();
    __threadfence();       // acquire side for all waves (shared CU L1)

    // ---- phase B: R10 deform body verbatim ----
    const int wave = tid >> 6;
    const int lane = tid & 63;
    const int quad = lane >> 4;
    const int col  = lane & 15;

    f32x4 acc00 = {0.f,0.f,0.f,0.f}, acc01 = {0.f,0.f,0.f,0.f};
    f32x4 acc10 = {0.f,0.f,0.f,0.f}, acc11 = {0.f,0.f,0.f,0.f};

    const unsigned short* bb16  = xb + ((size_t)bb << 19);
    const unsigned short* wbase = Wt + (wave << 10) + (lane << 3);

    const int ip0 = tid >> 4;
    const int ip1 = ip0 + 16;
    const int icg = (tid & 15) * 8;

    us8 ltA, rtA, lbA, rbA;
    us8 ltB, rtB, lbB, rbB;
    us8 bfr0, bfr1, bfr2, bfr3, bfr4, bfr5, bfr6, bfr7;

    ISSUE(0, ip0, A);
    int d = 0;

    for (int n = 0; n < KN; ++n, d ^= 1) {
        ISSUE(n, ip1, B);
        LOADB(n);
        CONSUME(n, ip0, A, d);
        CONSUME(n, ip1, B, d);

        BAR();
        // Hazard: As[d] next rewritten at tap n+2, after BAR(n+1) -- by which
        // point every wave's tap-n ds_reads are lgkm-drained. Safe.

        if (n + 1 < KN) ISSUE(n + 1, ip0, A);

        MTAP(d);
    }

    // ---- epilogue: C/D col=lane&15 -> filter, row=quad*4+reg -> pixel ----
    const int fbase = (wave << 5);
#pragma unroll
    for (int b = 0; b < 2; ++b) {
        int f = fbase + b * 16 + col;
        float bv = bias[f];
        const f32x4 ac0 = b ? acc01 : acc00;
        const f32x4 ac1 = b ? acc11 : acc10;
#pragma unroll
        for (int r = 0; r < 4; ++r) {
            int pr0 = pix0 + (quad << 2) + r;
            out[(size_t)pr0 * FF + f] = ac0[r] + bv;
            int pr1 = pr0 + 16;
            out[(size_t)pr1 * FF + f] = ac1[r] + bv;
        }
    }
}

extern "C" void kernel_launch(void* const* d_in, const int* in_sizes, int n_in,
                              void* d_out, int out_size, void* d_ws, size_t ws_size,
                              hipStream_t stream) {
    const float* x    = (const float*)d_in[0];
    const float* off  = (const float*)d_in[1];
    const float* Wk   = (const float*)d_in[2];
    const float* bias = (const float*)d_in[3];
    float* out = (float*)d_out;
    unsigned short* Wt = (unsigned short*)d_ws;            // 294912 B
    unsigned short* xb = (unsigned short*)d_ws + 147456;   // 8.4 MB bf16 x
    unsigned int* flag = (unsigned int*)((char*)d_ws + (16u << 20));

    hipMemsetAsync(flag, 0, 4, stream);   // stream-ordered, graph-capturable
    fused_kernel<<<NBLK, NT, 0, stream>>>(x, off, Wk, bias, out, Wt, xb, flag);
}

// Round 13
// 98.619 us; speedup vs baseline: 2.8472x; 2.8472x over previous
//
#include <hip/hip_runtime.h>
#include <stdint.h>

#define KN 9
#define CC 128
#define FF 128
#define TM 32      // pixels per block (half an image row)
#define NT 256     // threads per block (4 waves) -- small barrier domains
#define LDK 136    // padded LDS K-stride (bf16); 272 B row, 16B-aligned

typedef __bf16 bf16x8 __attribute__((ext_vector_type(8)));
typedef float f32x4 __attribute__((ext_vector_type(4)));
typedef unsigned short us8 __attribute__((ext_vector_type(8)));

__constant__ float c_init_i[KN] = {0.f,0.f,1.f,2.f,2.f,1.f,0.f,2.f,1.f};
__constant__ float c_init_j[KN] = {0.f,1.f,1.f,2.f,0.f,2.f,1.f,0.f,2.f};

static __device__ inline float bf2f(unsigned short u) {
    union { unsigned u; float f; } v; v.u = ((unsigned)u) << 16; return v.f;
}

// Merged prep: blocks 0..143 transpose W; blocks 144..2191 convert x to bf16.
// Wt bf16 fragment-linear layout: slot s = (n*4+ks)*8 + nt (nt = f>>4),
// elem = s*512 + quad*128 + col*8 + e, with f = nt*16 + col, c = ks*32+quad*8+e.
// Each wave's B-frag is one contiguous 1KB chunk (lane*16B): perfectly
// coalesced direct-from-L2 register loads in deform_kernel.
__global__ void prep_kernel(const float* __restrict__ Wk, unsigned short* __restrict__ Wt,
                            const float* __restrict__ x, unsigned short* __restrict__ xb) {
    __shared__ unsigned short t[32][33];
    const int tid = threadIdx.x;
    if (blockIdx.x >= 144) {
        int i = ((blockIdx.x - 144) * 256 + tid) * 8;
        float4 a = *(const float4*)(x + i);
        float4 b = *(const float4*)(x + i + 4);
        us8 o;
        o[0] = __builtin_bit_cast(unsigned short, (__bf16)a.x);
        o[1] = __builtin_bit_cast(unsigned short, (__bf16)a.y);
        o[2] = __builtin_bit_cast(unsigned short, (__bf16)a.z);
        o[3] = __builtin_bit_cast(unsigned short, (__bf16)a.w);
        o[4] = __builtin_bit_cast(unsigned short, (__bf16)b.x);
        o[5] = __builtin_bit_cast(unsigned short, (__bf16)b.y);
        o[6] = __builtin_bit_cast(unsigned short, (__bf16)b.z);
        o[7] = __builtin_bit_cast(unsigned short, (__bf16)b.w);
        *(us8*)(xb + i) = o;
        return;
    }
    const int n  = blockIdx.x >> 4;
    const int tf = blockIdx.x & 3;        // f-tile (2 nt slices)
    const int tc = (blockIdx.x >> 2) & 3; // c-tile (ks)
    const int g  = tid >> 5;
    const int l  = tid & 31;
#pragma unroll
    for (int r = 0; r < 4; ++r) {
        int cl = g * 4 + r;
        t[cl][l] = __builtin_bit_cast(unsigned short,
                    (__bf16)Wk[(n << 14) + ((tc * 32 + cl) << 7) + (tf * 32 + l)]);
    }
    __syncthreads();
#pragma unroll
    for (int r = 0; r < 4; ++r) {
        int o   = r * 256 + tid;          // 0..1023 within this (n,ks,tf) tile
        int b   = o >> 9;                 // nt = tf*2 + b
        int q   = (o >> 7) & 3;
        int col = (o >> 3) & 15;
        int e   = o & 7;
        Wt[(((n * 4 + tc) * 4 + tf) << 10) + o] = t[q * 8 + e][b * 16 + col];
    }
}

// issue 4 corner loads (8 bf16 channels) for pixel p_ into NAMED us8 regs
#define ISSUE(n_, p_, S) do {                                          \
    int lt_o = cB[p_][n_][0], rb_o = cB[p_][n_][1];                    \
    int rt_o = (rb_o & 0x7E000) | (lt_o & 0x1F80);                     \
    int lb_o = (lt_o & 0x7E000) | (rb_o & 0x1F80);                     \
    lt##S = *(const us8*)(bb16 + lt_o + icg);                          \
    rt##S = *(const us8*)(bb16 + rt_o + icg);                          \
    lb##S = *(const us8*)(bb16 + lb_o + icg);                          \
    rb##S = *(const us8*)(bb16 + rb_o + icg);                          \
    __builtin_amdgcn_sched_barrier(0);                                 \
  } while (0)

// bilinear interp of 8 channels + bf16 pack + one ds_write_b128
#define CONSUME(n_, p_, S, d_) do {                                    \
    float fy_ = cF[p_][n_][0], fx_ = cF[p_][n_][1];                    \
    us8 pk_;                                                           \
    _Pragma("unroll")                                                  \
    for (int j = 0; j < 8; ++j) {                                      \
      float v0_ = bf2f(lt##S[j]), v1_ = bf2f(rt##S[j]);                \
      float v2_ = bf2f(lb##S[j]), v3_ = bf2f(rb##S[j]);                \
      float vt_ = v0_ + (v1_ - v0_) * fy_;                             \
      float vb_ = v2_ + (v3_ - v2_) * fy_;                             \
      float r_  = vt_ + (vb_ - vt_) * fx_;                             \
      pk_[j] = __builtin_bit_cast(unsigned short, (__bf16)r_);         \
    }                                                                  \
    *(us8*)&As[d_][p_][icg] = pk_;                                     \
  } while (0)

// 8 B-fragments for tap n_ (this wave's 32-filter slice), direct from L2
#define LOADB(n_) do {                                                 \
    bfr0 = *(const us8*)(wbase + ((n_) << 14));                        \
    bfr1 = *(const us8*)(wbase + ((n_) << 14) + 512);                  \
    bfr2 = *(const us8*)(wbase + ((n_) << 14) + 4096);                 \
    bfr3 = *(const us8*)(wbase + ((n_) << 14) + 4096 + 512);           \
    bfr4 = *(const us8*)(wbase + ((n_) << 14) + 8192);                 \
    bfr5 = *(const us8*)(wbase + ((n_) << 14) + 8192 + 512);           \
    bfr6 = *(const us8*)(wbase + ((n_) << 14) + 12288);                \
    bfr7 = *(const us8*)(wbase + ((n_) << 14) + 12288 + 512);          \
    __builtin_amdgcn_sched_barrier(0);                                 \
  } while (0)

#define MSTEP(d_, ks_, B0, B1) do {                                    \
    bf16x8 a0_ = __builtin_bit_cast(bf16x8, *(const us8*)(&As[d_][col][(ks_) * 32 + quad * 8]));      \
    bf16x8 a1_ = __builtin_bit_cast(bf16x8, *(const us8*)(&As[d_][16 + col][(ks_) * 32 + quad * 8])); \
    acc00 = __builtin_amdgcn_mfma_f32_16x16x32_bf16(a0_, __builtin_bit_cast(bf16x8, B0), acc00, 0, 0, 0); \
    acc01 = __builtin_amdgcn_mfma_f32_16x16x32_bf16(a0_, __builtin_bit_cast(bf16x8, B1), acc01, 0, 0, 0); \
    acc10 = __builtin_amdgcn_mfma_f32_16x16x32_bf16(a1_, __builtin_bit_cast(bf16x8, B0), acc10, 0, 0, 0); \
    acc11 = __builtin_amdgcn_mfma_f32_16x16x32_bf16(a1_, __builtin_bit_cast(bf16x8, B1), acc11, 0, 0, 0); \
  } while (0)

#define MTAP(d_) do {                                                  \
    MSTEP(d_, 0, bfr0, bfr1); MSTEP(d_, 1, bfr2, bfr3);                \
    MSTEP(d_, 2, bfr4, bfr5); MSTEP(d_, 3, bfr6, bfr7);                \
  } while (0)

// lgkm-only barrier: drains ds_writes (As ready) and proves prior MFMA
// ds_reads done; global loads (gathers + B-frags) stay in flight across it.
#define BAR() do {                                                     \
    asm volatile("s_waitcnt lgkmcnt(0)" ::: "memory");                 \
    __builtin_amdgcn_s_barrier();                                      \
  } while (0)

// Optimum of the measured occupancy matrix (NT=256, cap=128): 4 blocks/CU x
// 4 waves = 16 waves/CU with FOUR independent barrier domains. Tighter caps
// (102, 85) spill the cross-barrier live set (R6/R7); single-launch fusion is
// dead on both mechanisms (R8: cooperative never executes under capture;
// R12: manual grid barrier costs 180us vs the ~15us of launches it replaces).
__launch_bounds__(NT, 4)
__global__ void deform_kernel(const unsigned short* __restrict__ xb,
                              const float* __restrict__ off,
                              const unsigned short* __restrict__ Wt,
                              const float* __restrict__ bias,
                              float* __restrict__ out) {
    __shared__ unsigned short As[2][TM][LDK];  // double-buffered: 8704 B
    __shared__ int   cB[TM][KN][2];            // packed lt/rb offsets: 2304 B
    __shared__ float cF[TM][KN][2];            // (fy, fx): 2304 B
    // total 22016 B; 4 blocks/CU -> 86 KB LDS of 160 KB

    const int tid = threadIdx.x;
    const int bb   = blockIdx.x & 7;           // XCD swizzle: image b -> XCD b
    const int rr   = blockIdx.x >> 3;          // 0..127: 32-pixel chunk
    const int pix0 = (bb << 12) + (rr << 5);

    // ---- phase 0: packed corner offsets + fractions per (p, n) ----
    for (int t = tid; t < TM * KN; t += NT) {   // 288 entries, 2 passes
        int p = t & (TM - 1);
        int n = t >> 5;
        int pg = (rr << 5) + p;                 // pixel index within image
        float2 o = *(const float2*)(off + (size_t)(pix0 + p) * (2 * KN) + 2 * n);
        float y = (float)((pg >> 6) - 1) + c_init_i[n] + o.x;
        float x = (float)((pg & 63) - 1) + c_init_j[n] + o.y;
        y = fminf(fmaxf(y, 0.f), 63.f);
        x = fminf(fmaxf(x, 0.f), 63.f);
        float y0f = floorf(y), x0f = floorf(x);
        int y0 = (int)y0f, x0 = (int)x0f;
        int y1 = (int)ceilf(y), x1 = (int)ceilf(x);
        cB[p][n][0] = (y0 << 13) | (x0 << 7);   // lt element offset
        cB[p][n][1] = (y1 << 13) | (x1 << 7);   // rb element offset
        cF[p][n][0] = y - y0f;
        cF[p][n][1] = x - x0f;
    }

    const int wave = tid >> 6;                  // 0..3: owns 32 filters
    const int lane = tid & 63;
    const int quad = lane >> 4;
    const int col  = lane & 15;

    f32x4 acc00 = {0.f,0.f,0.f,0.f}, acc01 = {0.f,0.f,0.f,0.f};
    f32x4 acc10 = {0.f,0.f,0.f,0.f}, acc11 = {0.f,0.f,0.f,0.f};

    const unsigned short* bb16  = xb + ((size_t)bb << 19);
    const unsigned short* wbase = Wt + (wave << 10) + (lane << 3);

    // gather: 2 items/thread/tap: pixels ip0, ip0+16; channels icg..icg+7
    const int ip0 = tid >> 4;          // 0..15
    const int ip1 = ip0 + 16;
    const int icg = (tid & 15) * 8;

    us8 ltA, rtA, lbA, rbA;      // item-0 set (cross-tap prefetched)
    us8 ltB, rtB, lbB, rbB;      // item-1 set
    us8 bfr0, bfr1, bfr2, bfr3, bfr4, bfr5, bfr6, bfr7;

    __syncthreads();   // coords ready

    ISSUE(0, ip0, A);  // prologue: tap 0, item 0
    int d = 0;

    for (int n = 0; n < KN; ++n, d ^= 1) {
        ISSUE(n, ip1, B);
        LOADB(n);                 // rides until MTAP (post-barrier)
        CONSUME(n, ip0, A, d);    // item 0 arrived during prior MFMA phase
        CONSUME(n, ip1, B, d);

        BAR();
        // Hazard: As[d] written above, read by MTAP below; As[d] is next
        // rewritten at tap n+2, after BAR(n+1) -- by which point every
        // wave's tap-n reads are lgkm-drained (its own BAR(n+1) wait).

        if (n + 1 < KN) ISSUE(n + 1, ip0, A);   // flies under MFMA phase

        MTAP(d);
    }

    // ---- epilogue: C/D col=lane&15 -> filter, row=quad*4+reg -> pixel ----
    const int fbase = (wave << 5);
#pragma unroll
    for (int b = 0; b < 2; ++b) {
        int f = fbase + b * 16 + col;
        float bv = bias[f];
        const f32x4 ac0 = b ? acc01 : acc00;
        const f32x4 ac1 = b ? acc11 : acc10;
#pragma unroll
        for (int r = 0; r < 4; ++r) {
            int pr0 = pix0 + (quad << 2) + r;
            out[(size_t)pr0 * FF + f] = ac0[r] + bv;
            int pr1 = pr0 + 16;
            out[(size_t)pr1 * FF + f] = ac1[r] + bv;
        }
    }
}

extern "C" void kernel_launch(void* const* d_in, const int* in_sizes, int n_in,
                              void* d_out, int out_size, void* d_ws, size_t ws_size,
                              hipStream_t stream) {
    const float* x    = (const float*)d_in[0];
    const float* off  = (const float*)d_in[1];
    const float* Wk   = (const float*)d_in[2];
    const float* bias = (const float*)d_in[3];
    float* out = (float*)d_out;
    unsigned short* Wt = (unsigned short*)d_ws;            // 294912 B
    unsigned short* xb = (unsigned short*)d_ws + 147456;   // 8 MB bf16 x

    prep_kernel<<<144 + 2048, 256, 0, stream>>>(Wk, Wt, x, xb);
    deform_kernel<<<(8 * 64 * 64) / TM, NT, 0, stream>>>(xb, off, Wt, bias, out);
}